// Round 8
// baseline (227.505 us; speedup 1.0000x reference)
//
#include <hip/hip_runtime.h>
#include <hip/hip_fp16.h>

typedef unsigned short u16;
using f32x4 = __attribute__((ext_vector_type(4))) float;
using half8 = __attribute__((ext_vector_type(8))) _Float16;
using us8   = __attribute__((ext_vector_type(8))) unsigned short;
using us4   = __attribute__((ext_vector_type(4))) unsigned short;

#define N_PTS 8192
#define D_DIM 768
#define TOPK  21
#define KSTEPS 12
#define CAPL  8
#define CAPG  448

// ---------------- async global->LDS (16B per lane) ----------------
__device__ __forceinline__ void gload16(const void* g, void* l) {
    __builtin_amdgcn_global_load_lds(
        (const __attribute__((address_space(1))) void*)g,
        (__attribute__((address_space(3))) void*)l,
        16, 0, 0);
}

// ---------------- wave (64-lane) reductions ----------------
__device__ __forceinline__ int wred_sum_i(int c) {
#pragma unroll
    for (int o = 32; o >= 1; o >>= 1) c += __shfl_xor(c, o, 64);
    return c;
}
__device__ __forceinline__ float wred_sum_f(float c) {
#pragma unroll
    for (int o = 32; o >= 1; o >>= 1) c += __shfl_xor(c, o, 64);
    return c;
}
__device__ __forceinline__ float wred_min_f(float c) {
#pragma unroll
    for (int o = 32; o >= 1; o >>= 1) c = fminf(c, __shfl_xor(c, o, 64));
    return c;
}

// ---------------- kernel 1: fp32 -> fp16 + row norms (vectorized) ----
// 2048 blocks x 256 thr; one wave per row (4 rows/block).
__global__ __launch_bounds__(256) void prep_kernel(const float* __restrict__ X,
                                                   u16* __restrict__ Xh,
                                                   float* __restrict__ norms,
                                                   int* __restrict__ cnt_g) {
    const int tid  = threadIdx.x;
    const int lane = tid & 63;
    const int row  = blockIdx.x * 4 + (tid >> 6);
    const float4* xr = (const float4*)(X + (size_t)row * D_DIM);
    us4* hr = (us4*)(Xh + (size_t)row * D_DIM);
    float s = 0.f;
#pragma unroll
    for (int j = 0; j < 3; ++j) {
        const float4 v = xr[lane + j * 64];
        _Float16 h0 = (_Float16)v.x, h1 = (_Float16)v.y,
                 h2 = (_Float16)v.z, h3 = (_Float16)v.w;
        us4 u;
        u[0] = __builtin_bit_cast(u16, h0);
        u[1] = __builtin_bit_cast(u16, h1);
        u[2] = __builtin_bit_cast(u16, h2);
        u[3] = __builtin_bit_cast(u16, h3);
        hr[lane + j * 64] = u;
        const float f0 = (float)h0, f1 = (float)h1, f2 = (float)h2, f3 = (float)h3;
        s += f0 * f0 + f1 * f1 + f2 * f2 + f3 * f3;
    }
#pragma unroll
    for (int o = 32; o >= 1; o >>= 1) s += __shfl_down(s, o, 64);
    if (lane == 0) {
        norms[row] = s;
        cnt_g[row] = 0;
    }
}

// ---------------- unified 128x128 4-phase counted-vmcnt GEMM core ----
// MODE 0: tau sample GEMM (rows x cols 0..1023) -> d2h fp16.
// MODE 1: symmetric upper-triangle full GEMM + two-sided threshold filter.
// 256 thr = 4 waves (2M x 2N), per-wave C = 64x64, BK=64.
// LDS slots [slot][khalf][128][32] f16; stage rounds = contiguous LDS ranges:
// r0=A-k0, r1=B-k0, r2=A-k1, r3=B-k1 (2 gload16/thread each).
// Phase q=(ks=q>>1, nh=q&1): waits vmcnt(4/6/4/6), barrier, stage round q of
// K-tile kt+1, ds_read frags, 8 MFMA. Loads get 3-4 phases of cover.
template<int MODE>
__global__ __launch_bounds__(256, 2) void gemm_core(const u16* __restrict__ Xh,
                                                    const float* __restrict__ norms,
                                                    const float* __restrict__ tauB,
                                                    u16* __restrict__ d2h,
                                                    float* __restrict__ cand_g,
                                                    int* __restrict__ cnt_g) {
    __shared__ __align__(16) u16 As[2][2][128][32];   // 32 KiB
    __shared__ __align__(16) u16 Bs[2][2][128][32];   // 32 KiB
    __shared__ float nAs[128], nBs[128], tA[128], tB[128];
    __shared__ float candR[128 * CAPL], candC[128 * CAPL];
    __shared__ int   cntR[128], cntC[128];

    const int tid  = threadIdx.x;
    const int lane = tid & 63;
    const int wid  = tid >> 6;
    const int wr   = wid >> 1;
    const int wc   = wid & 1;
    const int l16  = lane >> 4;
    const int l15  = lane & 15;

    int r0, c0;
    bool diag = false;
    if (MODE == 0) {                 // 512 = 8*64 XCD-bijective
        const int swz = (blockIdx.x & 7) * 64 + (blockIdx.x >> 3);
        r0 = (swz >> 3) * 128;
        c0 = (swz & 7) * 128;
    } else {                         // 2080 = 8*260; triangular b = j(j+1)/2 + i
        const int b = (blockIdx.x & 7) * 260 + (blockIdx.x >> 3);
        int j = (int)((sqrtf(8.0f * (float)b + 1.0f) - 1.0f) * 0.5f);
        while ((j + 1) * (j + 2) / 2 <= b) ++j;
        while (j * (j + 1) / 2 > b) --j;
        const int i = b - j * (j + 1) / 2;
        r0 = i * 128;
        c0 = j * 128;
        diag = (i == j);
    }

    if (tid < 128) {
        nAs[tid] = norms[r0 + tid];
        nBs[tid] = norms[c0 + tid];
        if (MODE == 1) {
            tA[tid] = tauB[r0 + tid];
            tB[tid] = tauB[c0 + tid];
            cntR[tid] = 0;
            cntC[tid] = 0;
        }
    }

    f32x4 acc[4][4];
#pragma unroll
    for (int m = 0; m < 4; ++m)
#pragma unroll
        for (int n = 0; n < 4; ++n) {
            f32x4 z = {0.f, 0.f, 0.f, 0.f};
            acc[m][n] = z;
        }

    // stage round r of K-tile tt into slot s (tt=12 reads garbage in-ws: safe)
    auto SROUND = [&](int tt, int s, int r) {
        const int kh = r >> 1;
        const u16* src = Xh + (size_t)((r & 1) ? c0 : r0) * D_DIM;
        u16 (*dst)[128][32] = (r & 1) ? Bs[s] : As[s];
#pragma unroll
        for (int sub = 0; sub < 2; ++sub) {
            const int idx = sub * 256 + tid;
            const int row = idx >> 2;
            const int ch  = idx & 3;
            const int gch = kh * 4 + (ch ^ ((row >> 1) & 3));
            gload16(src + (size_t)row * D_DIM + tt * 64 + gch * 8,
                    &dst[kh][row][ch * 8]);
        }
    };

    __syncthreads();                 // drain norm loads -> clean vmcnt baseline

#pragma unroll
    for (int r = 0; r < 4; ++r) SROUND(0, 0, r);

    for (int kt = 0; kt < KSTEPS; ++kt) {
        const int sl = kt & 1;
        const int ss = sl ^ 1;
        const int tt = kt + 1;
        half8 af[4];
#pragma unroll
        for (int q = 0; q < 4; ++q) {
            const int ks = q >> 1;
            const int nh = q & 1;
            // counted waits: phase-q rounds were issued 3-4 phases ago
            if (nh) { asm volatile("s_waitcnt vmcnt(6)" ::: "memory"); }
            else    { asm volatile("s_waitcnt vmcnt(4)" ::: "memory"); }
            __builtin_amdgcn_sched_barrier(0);
            __builtin_amdgcn_s_barrier();
            __builtin_amdgcn_sched_barrier(0);

            SROUND(tt, ss, q);       // prefetch round q of next K-tile

            if (nh == 0) {
#pragma unroll
                for (int m = 0; m < 4; ++m) {
                    const int row = wr * 64 + m * 16 + l15;
                    const int ch  = l16 ^ ((row >> 1) & 3);
                    af[m] = *(const half8*)&As[sl][ks][row][ch * 8];
                }
            }
            half8 bf[2];
#pragma unroll
            for (int nn = 0; nn < 2; ++nn) {
                const int row = wc * 64 + (nh * 2 + nn) * 16 + l15;
                const int ch  = l16 ^ ((row >> 1) & 3);
                bf[nn] = *(const half8*)&Bs[sl][ks][row][ch * 8];
            }
            __builtin_amdgcn_s_setprio(1);
#pragma unroll
            for (int m = 0; m < 4; ++m)
#pragma unroll
                for (int nn = 0; nn < 2; ++nn)
                    acc[m][nh * 2 + nn] = __builtin_amdgcn_mfma_f32_16x16x32_f16(
                        af[m], bf[nn], acc[m][nh * 2 + nn], 0, 0, 0);
            __builtin_amdgcn_s_setprio(0);
        }
    }
    asm volatile("s_waitcnt vmcnt(0)" ::: "memory");   // drain kt=12 garbage stages

    if (MODE == 0) {
        // ---- tau epilogue: d2 -> fp16 store ----
        float nBc[4];
#pragma unroll
        for (int n = 0; n < 4; ++n) nBc[n] = nBs[wc * 64 + n * 16 + l15];
#pragma unroll
        for (int m = 0; m < 4; ++m)
#pragma unroll
            for (int r = 0; r < 4; ++r) {
                const int ra = wr * 64 + m * 16 + l16 * 4 + r;
                const float na = nAs[ra];
#pragma unroll
                for (int n = 0; n < 4; ++n) {
                    const int ci = c0 + wc * 64 + n * 16 + l15;
                    float d2 = fmaxf(na + nBc[n] - 2.0f * acc[m][n][r], 0.0f);
                    _Float16 h = (_Float16)d2;
                    d2h[(size_t)(r0 + ra) * 1024 + ci] = __builtin_bit_cast(u16, h);
                }
            }
    } else {
        // ---- two-sided filter epilogue (R6-proven) ----
        float nBc[4], tBc[4];
#pragma unroll
        for (int n = 0; n < 4; ++n) {
            const int ci = wc * 64 + n * 16 + l15;
            nBc[n] = nBs[ci];
            tBc[n] = tB[ci];
        }
#pragma unroll
        for (int m = 0; m < 4; ++m)
#pragma unroll
            for (int r = 0; r < 4; ++r) {
                const int ri = wr * 64 + m * 16 + l16 * 4 + r;
                const float na = nAs[ri];
                const float ta = tA[ri];
#pragma unroll
                for (int n = 0; n < 4; ++n) {
                    const float val = na + nBc[n] - 2.0f * acc[m][n][r];
                    if (val < ta) {                      // row-side
                        const int idx = atomicAdd(&cntR[ri], 1);
                        if (idx < CAPL) candR[ri * CAPL + idx] = val;
                        else {
                            const int g = atomicAdd(&cnt_g[r0 + ri], 1);
                            if (g < CAPG) cand_g[(size_t)(r0 + ri) * CAPG + g] = val;
                        }
                    }
                    if (!diag && val < tBc[n]) {         // col-side (symmetry)
                        const int ci = wc * 64 + n * 16 + l15;
                        const int idx = atomicAdd(&cntC[ci], 1);
                        if (idx < CAPL) candC[ci * CAPL + idx] = val;
                        else {
                            const int g = atomicAdd(&cnt_g[c0 + ci], 1);
                            if (g < CAPG) cand_g[(size_t)(c0 + ci) * CAPG + g] = val;
                        }
                    }
                }
            }

        __syncthreads();
        if (tid < 128) {
            {
                const int row = r0 + tid;
                const int c = (cntR[tid] < CAPL) ? cntR[tid] : CAPL;
                if (c > 0) {
                    const int base = atomicAdd(&cnt_g[row], c);
                    for (int qq = 0; qq < c; ++qq) {
                        const int s = base + qq;
                        if (s < CAPG) cand_g[(size_t)row * CAPG + s] = candR[tid * CAPL + qq];
                    }
                }
            }
            if (!diag) {
                const int row = c0 + tid;
                const int c = (cntC[tid] < CAPL) ? cntC[tid] : CAPL;
                if (c > 0) {
                    const int base = atomicAdd(&cnt_g[row], c);
                    for (int qq = 0; qq < c; ++qq) {
                        const int s = base + qq;
                        if (s < CAPG) cand_g[(size_t)row * CAPG + s] = candC[tid * CAPL + qq];
                    }
                }
            }
        }
    }
}

// ---------------- kernel 3: per-row 21st-smallest of sample (bit search) ----
__global__ __launch_bounds__(256) void tau_select_kernel(const u16* __restrict__ d2h,
                                                         float* __restrict__ tauB) {
    const int tid  = threadIdx.x;
    const int lane = tid & 63;
    const int row  = blockIdx.x * 4 + (tid >> 6);

    const us8* p = (const us8*)(d2h + (size_t)row * 1024);
    us8 v0 = p[lane * 2];
    us8 v1 = p[lane * 2 + 1];

    unsigned lo = 0, hi = 0x7BFF;
#pragma unroll
    for (int it = 0; it < 15; ++it) {
        const unsigned mid = (lo + hi) >> 1;
        int c = 0;
#pragma unroll
        for (int j = 0; j < 8; ++j) c += ((unsigned)v0[j] <= mid) + ((unsigned)v1[j] <= mid);
        c = wred_sum_i(c);
        if (c >= TOPK) hi = mid; else lo = mid + 1;
    }
    if (lane == 0) {
        u16 b = (u16)lo;
        _Float16 h = __builtin_bit_cast(_Float16, b);
        tauB[row] = (float)h + 2.0f;   // upper bound on true 21st d2 + fp16 slack
    }
}

// ---------------- kernel 5: per-row top-21 stats + LID ----
__global__ __launch_bounds__(256) void finalize_kernel(const float* __restrict__ cand_g,
                                                       const int* __restrict__ cnt_g,
                                                       float* __restrict__ out) {
    const int tid  = threadIdx.x;
    const int lane = tid & 63;
    const int row  = blockIdx.x * 4 + (tid >> 6);

    int cnt = cnt_g[row];
    if (cnt > CAPG) cnt = CAPG;
    const float INFV = __uint_as_float(0x7F800000u);

    float v[7];
    unsigned b[7];
#pragma unroll
    for (int j = 0; j < 7; ++j) {
        const int s = lane + 64 * j;
        v[j] = (s < cnt) ? fmaxf(cand_g[(size_t)row * CAPG + s], 0.0f) : INFV;
        b[j] = __float_as_uint(v[j]);
    }

    unsigned lo = 0, hi = 0x7F7FFFFFu;
#pragma unroll
    for (int it = 0; it < 31; ++it) {
        const unsigned mid = (lo + hi) >> 1;
        int c = 0;
#pragma unroll
        for (int j = 0; j < 7; ++j) c += (b[j] <= mid);
        c = wred_sum_i(c);
        if (c >= TOPK) hi = mid; else lo = mid + 1;
    }
    const float th = __uint_as_float(lo);

    int clt = 0;
    float slt = 0.f, mn = INFV;
#pragma unroll
    for (int j = 0; j < 7; ++j) {
        if (b[j] < lo) {
            clt += 1;
            slt += sqrtf(fmaxf(v[j], 1e-12f));
        }
        mn = fminf(mn, v[j]);
    }
    clt = wred_sum_i(clt);
    slt = wred_sum_f(slt);
    mn  = wred_min_f(mn);

    if (lane == 0) {
        const float a20 = sqrtf(fmaxf(th, 1e-12f));
        const float a0  = sqrtf(fmaxf(mn, 1e-12f));
        const float S21 = slt + (float)(TOPK - clt) * a20;
        const float m   = (S21 - a0 - a20) * (1.0f / 19.0f);
        const float lid = m / (a20 - m);
        out[row] = -fabsf(logf(lid));
    }
}

extern "C" void kernel_launch(void* const* d_in, const int* in_sizes, int n_in,
                              void* d_out, int out_size, void* d_ws, size_t ws_size,
                              hipStream_t stream) {
    const float* X = (const float*)d_in[0];
    float* out = (float*)d_out;
    char* ws = (char*)d_ws;

    u16*   Xh    = (u16*)ws;                      // 12,582,912 B
    float* norms = (float*)(ws + 12582912);       //     32,768 B
    float* tauB  = (float*)(ws + 12615680);       //     32,768 B
    int*   cnt_g = (int*)(ws + 12648448);         //     32,768 B
    u16*   d2h   = (u16*)(ws + 12681216);         // 16,777,216 B (8192x1024 fp16)
    float* cand_g = (float*)(ws + 12681216);      // 14,680,064 B, aliases d2h

    prep_kernel<<<N_PTS / 4, 256, 0, stream>>>(X, Xh, norms, cnt_g);
    gemm_core<0><<<512, 256, 0, stream>>>(Xh, norms, nullptr, d2h, nullptr, nullptr);
    tau_select_kernel<<<N_PTS / 4, 256, 0, stream>>>(d2h, tauB);
    gemm_core<1><<<2080, 256, 0, stream>>>(Xh, norms, tauB, nullptr, cand_g, cnt_g);
    finalize_kernel<<<N_PTS / 4, 256, 0, stream>>>(cand_g, cnt_g, out);
}

// Round 9
// 181.417 us; speedup vs baseline: 1.2540x; 1.2540x over previous
//
#include <hip/hip_runtime.h>
#include <hip/hip_fp16.h>

typedef unsigned short u16;
using f32x4 = __attribute__((ext_vector_type(4))) float;
using half8 = __attribute__((ext_vector_type(8))) _Float16;
using us8   = __attribute__((ext_vector_type(8))) unsigned short;
using us4   = __attribute__((ext_vector_type(4))) unsigned short;

#define N_PTS 8192
#define D_DIM 768
#define TOPK  21
#define KSTEPS 12
#define CAPL  4          // LDS candidate slots/row/tile-side (E=0.33, P(>4)~1e-5)
#define CAPG  448        // global candidate slots per row (E~168)

// ---------------- async global->LDS (16B per lane) ----------------
__device__ __forceinline__ void gload16(const void* g, void* l) {
    __builtin_amdgcn_global_load_lds(
        (const __attribute__((address_space(1))) void*)g,
        (__attribute__((address_space(3))) void*)l,
        16, 0, 0);
}

// ---------------- wave (64-lane) reductions ----------------
__device__ __forceinline__ int wred_sum_i(int c) {
#pragma unroll
    for (int o = 32; o >= 1; o >>= 1) c += __shfl_xor(c, o, 64);
    return c;
}
__device__ __forceinline__ float wred_sum_f(float c) {
#pragma unroll
    for (int o = 32; o >= 1; o >>= 1) c += __shfl_xor(c, o, 64);
    return c;
}
__device__ __forceinline__ float wred_min_f(float c) {
#pragma unroll
    for (int o = 32; o >= 1; o >>= 1) c = fminf(c, __shfl_xor(c, o, 64));
    return c;
}

// ---------------- kernel 1: fp32 -> fp16 + row norms (vectorized) ----
// 2048 blocks x 256 thr; one wave per row.
__global__ __launch_bounds__(256) void prep_kernel(const float* __restrict__ X,
                                                   u16* __restrict__ Xh,
                                                   float* __restrict__ norms,
                                                   int* __restrict__ cnt_g) {
    const int tid  = threadIdx.x;
    const int lane = tid & 63;
    const int row  = blockIdx.x * 4 + (tid >> 6);
    const float4* xr = (const float4*)(X + (size_t)row * D_DIM);
    us4* hr = (us4*)(Xh + (size_t)row * D_DIM);
    float s = 0.f;
#pragma unroll
    for (int j = 0; j < 3; ++j) {
        const float4 v = xr[lane + j * 64];
        _Float16 h0 = (_Float16)v.x, h1 = (_Float16)v.y,
                 h2 = (_Float16)v.z, h3 = (_Float16)v.w;
        us4 u;
        u[0] = __builtin_bit_cast(u16, h0);
        u[1] = __builtin_bit_cast(u16, h1);
        u[2] = __builtin_bit_cast(u16, h2);
        u[3] = __builtin_bit_cast(u16, h3);
        hr[lane + j * 64] = u;
        const float f0 = (float)h0, f1 = (float)h1, f2 = (float)h2, f3 = (float)h3;
        s += f0 * f0 + f1 * f1 + f2 * f2 + f3 * f3;
    }
#pragma unroll
    for (int o = 32; o >= 1; o >>= 1) s += __shfl_down(s, o, 64);
    if (lane == 0) {
        norms[row] = s;
        cnt_g[row] = 0;
    }
}

// ---------------- kernel 2: sample GEMM (cols 0..1023) -> d2 as fp16 ----
// R3-proven 128x128 single-buffer structure; 512 blocks.
__global__ __launch_bounds__(256, 4) void gemm_tau_kernel(const u16* __restrict__ Xh,
                                                          const float* __restrict__ norms,
                                                          u16* __restrict__ d2h) {
    __shared__ __align__(16) u16 As[128 * 64];
    __shared__ __align__(16) u16 Bs[128 * 64];
    __shared__ float nAs[128];
    __shared__ float nBs[128];

    const int tid  = threadIdx.x;
    const int lane = tid & 63;
    const int wid  = tid >> 6;
    const int wr   = wid >> 1;
    const int wc   = wid & 1;
    const int l16  = lane >> 4;
    const int l15  = lane & 15;

    const int bid = blockIdx.x;
    const int swz = (bid & 7) * 64 + (bid >> 3);
    const int rowTile = swz >> 3;
    const int chunk   = swz & 7;
    const int r0 = rowTile * 128;
    const int cb = chunk * 128;

    if (tid < 128) {
        nAs[tid] = norms[r0 + tid];
        nBs[tid] = norms[cb + tid];
    }

    const int rb   = tid >> 3;
    const int cole = (tid & 7) * 8;
    const int lofs = tid * 8;

    f32x4 acc[4][4];
#pragma unroll
    for (int m = 0; m < 4; ++m)
#pragma unroll
        for (int n = 0; n < 4; ++n) {
            f32x4 z = {0.f, 0.f, 0.f, 0.f};
            acc[m][n] = z;
        }

    for (int ks = 0; ks < KSTEPS; ++ks) {
        const int kofs = ks * 64;
#pragma unroll
        for (int i = 0; i < 4; ++i) {
            const int r = i * 32 + rb;
            gload16(Xh + (size_t)(r0 + r) * D_DIM + kofs + cole, &As[i * 2048 + lofs]);
            gload16(Xh + (size_t)(cb + r) * D_DIM + kofs + cole, &Bs[i * 2048 + lofs]);
        }
        __syncthreads();
#pragma unroll
        for (int kk = 0; kk < 2; ++kk) {
            const int ko = kk * 32 + l16 * 8;
            half8 af[4], bf[4];
#pragma unroll
            for (int m = 0; m < 4; ++m)
                af[m] = *reinterpret_cast<const half8*>(&As[(wr * 64 + m * 16 + l15) * 64 + ko]);
#pragma unroll
            for (int n = 0; n < 4; ++n)
                bf[n] = *reinterpret_cast<const half8*>(&Bs[(wc * 64 + n * 16 + l15) * 64 + ko]);
#pragma unroll
            for (int m = 0; m < 4; ++m)
#pragma unroll
                for (int n = 0; n < 4; ++n)
                    acc[m][n] = __builtin_amdgcn_mfma_f32_16x16x32_f16(af[m], bf[n], acc[m][n], 0, 0, 0);
        }
        __syncthreads();
    }

    float nAr[4][4], nBc[4];
#pragma unroll
    for (int m = 0; m < 4; ++m)
#pragma unroll
        for (int r = 0; r < 4; ++r) nAr[m][r] = nAs[wr * 64 + m * 16 + l16 * 4 + r];
#pragma unroll
    for (int n = 0; n < 4; ++n) nBc[n] = nBs[wc * 64 + n * 16 + l15];

#pragma unroll
    for (int m = 0; m < 4; ++m)
#pragma unroll
        for (int n = 0; n < 4; ++n)
#pragma unroll
            for (int r = 0; r < 4; ++r) {
                const int ri = r0 + wr * 64 + m * 16 + l16 * 4 + r;
                const int ci = cb + wc * 64 + n * 16 + l15;
                float d2 = fmaxf(nAr[m][r] + nBc[n] - 2.0f * acc[m][n][r], 0.0f);
                _Float16 h = (_Float16)d2;
                d2h[(size_t)ri * 1024 + ci] = __builtin_bit_cast(u16, h);
            }
}

// ---------------- kernel 3: per-row 21st-smallest of sample (bit search) ----
__global__ __launch_bounds__(256) void tau_select_kernel(const u16* __restrict__ d2h,
                                                         float* __restrict__ tauB) {
    const int tid  = threadIdx.x;
    const int lane = tid & 63;
    const int row  = blockIdx.x * 4 + (tid >> 6);

    const us8* p = (const us8*)(d2h + (size_t)row * 1024);
    us8 v0 = p[lane * 2];
    us8 v1 = p[lane * 2 + 1];

    unsigned lo = 0, hi = 0x7BFF;
#pragma unroll
    for (int it = 0; it < 15; ++it) {
        const unsigned mid = (lo + hi) >> 1;
        int c = 0;
#pragma unroll
        for (int j = 0; j < 8; ++j) c += ((unsigned)v0[j] <= mid) + ((unsigned)v1[j] <= mid);
        c = wred_sum_i(c);
        if (c >= TOPK) hi = mid; else lo = mid + 1;
    }
    if (lane == 0) {
        u16 b = (u16)lo;
        _Float16 h = __builtin_bit_cast(_Float16, b);
        tauB[row] = (float)h + 2.0f;   // upper bound on true 21st d2 + fp16 slack
    }
}

// ---------------- kernel 4: SYMMETRIC upper-triangle GEMM + two-sided filter ----
// 2080 = 64*65/2 tiles of 128x128 (i<=j); off-diag tiles emit row- AND col-side.
// LDS 39,936 B -> 4 blocks/CU.
__global__ __launch_bounds__(256, 4) void gemm_filter_sym(const u16* __restrict__ Xh,
                                                          const float* __restrict__ norms,
                                                          const float* __restrict__ tauB,
                                                          float* __restrict__ cand_g,
                                                          int* __restrict__ cnt_g) {
    __shared__ __align__(16) u16 As[128 * 64];       // 16 KiB
    __shared__ __align__(16) u16 Bs[128 * 64];       // 16 KiB
    __shared__ float candR[128 * CAPL];              // 2 KiB
    __shared__ float candC[128 * CAPL];              // 2 KiB
    __shared__ int   cntR[128];
    __shared__ int   cntC[128];
    __shared__ float nAs[128], nBs[128], tA[128], tB[128];

    const int tid  = threadIdx.x;
    const int lane = tid & 63;
    const int wid  = tid >> 6;
    const int wr   = wid >> 1;
    const int wc   = wid & 1;
    const int l16  = lane >> 4;
    const int l15  = lane & 15;

    // XCD swizzle (2080 = 8 * 260) then triangular decode: b = j*(j+1)/2 + i, i<=j
    const int b = (blockIdx.x & 7) * 260 + (blockIdx.x >> 3);
    int j = (int)((sqrtf(8.0f * (float)b + 1.0f) - 1.0f) * 0.5f);
    while ((j + 1) * (j + 2) / 2 <= b) ++j;
    while (j * (j + 1) / 2 > b) --j;
    const int i = b - j * (j + 1) / 2;
    const int r0 = i * 128;
    const int c0 = j * 128;
    const bool diag = (i == j);

    if (tid < 128) {
        nAs[tid] = norms[r0 + tid];
        tA[tid]  = tauB[r0 + tid];
        nBs[tid] = norms[c0 + tid];
        tB[tid]  = tauB[c0 + tid];
        cntR[tid] = 0;
        cntC[tid] = 0;
    }

    // staging geometry: 8 lanes per 128B row; T2 source-side XOR swizzle
    const int rb  = tid >> 3;
    const int chS = (tid & 7) ^ ((tid >> 3) & 7);
    const int lofs = tid * 8;

    f32x4 acc[4][4];
#pragma unroll
    for (int m = 0; m < 4; ++m)
#pragma unroll
        for (int n = 0; n < 4; ++n) {
            f32x4 z = {0.f, 0.f, 0.f, 0.f};
            acc[m][n] = z;
        }

    for (int ks = 0; ks < KSTEPS; ++ks) {
        const int kofs = ks * 64 + chS * 8;
#pragma unroll
        for (int it = 0; it < 4; ++it) {
            const int r = it * 32 + rb;
            gload16(Xh + (size_t)(r0 + r) * D_DIM + kofs, &As[it * 2048 + lofs]);
            gload16(Xh + (size_t)(c0 + r) * D_DIM + kofs, &Bs[it * 2048 + lofs]);
        }
        __syncthreads();
#pragma unroll
        for (int kk = 0; kk < 2; ++kk) {
            half8 af[4], bf[4];
#pragma unroll
            for (int m = 0; m < 4; ++m) {
                const int ra = wr * 64 + m * 16 + l15;
                const int ch = (kk * 4 + l16) ^ (ra & 7);
                af[m] = *reinterpret_cast<const half8*>(&As[ra * 64 + ch * 8]);
            }
#pragma unroll
            for (int n = 0; n < 4; ++n) {
                const int rc = wc * 64 + n * 16 + l15;
                const int ch = (kk * 4 + l16) ^ (rc & 7);
                bf[n] = *reinterpret_cast<const half8*>(&Bs[rc * 64 + ch * 8]);
            }
#pragma unroll
            for (int m = 0; m < 4; ++m)
#pragma unroll
                for (int n = 0; n < 4; ++n)
                    acc[m][n] = __builtin_amdgcn_mfma_f32_16x16x32_f16(af[m], bf[n], acc[m][n], 0, 0, 0);
        }
        __syncthreads();
    }

    // ---- two-sided filter epilogue ----
    float nBc[4], tBc[4];
#pragma unroll
    for (int n = 0; n < 4; ++n) {
        const int ci = wc * 64 + n * 16 + l15;
        nBc[n] = nBs[ci];
        tBc[n] = tB[ci];
    }

#pragma unroll
    for (int m = 0; m < 4; ++m)
#pragma unroll
        for (int r = 0; r < 4; ++r) {
            const int ri = wr * 64 + m * 16 + l16 * 4 + r;
            const float na = nAs[ri];
            const float ta = tA[ri];
#pragma unroll
            for (int n = 0; n < 4; ++n) {
                const float val = na + nBc[n] - 2.0f * acc[m][n][r];
                if (val < ta) {                      // row-side candidate
                    const int idx = atomicAdd(&cntR[ri], 1);
                    if (idx < CAPL) candR[ri * CAPL + idx] = val;
                    else {
                        const int g = atomicAdd(&cnt_g[r0 + ri], 1);
                        if (g < CAPG) cand_g[(size_t)(r0 + ri) * CAPG + g] = val;
                    }
                }
                if (!diag && val < tBc[n]) {         // col-side candidate (symmetry)
                    const int ci = wc * 64 + n * 16 + l15;
                    const int idx = atomicAdd(&cntC[ci], 1);
                    if (idx < CAPL) candC[ci * CAPL + idx] = val;
                    else {
                        const int g = atomicAdd(&cnt_g[c0 + ci], 1);
                        if (g < CAPG) cand_g[(size_t)(c0 + ci) * CAPG + g] = val;
                    }
                }
            }
        }

    __syncthreads();
    if (tid < 128) {
        {   // row-side writeout
            const int row = r0 + tid;
            const int c = (cntR[tid] < CAPL) ? cntR[tid] : CAPL;
            if (c > 0) {
                const int base = atomicAdd(&cnt_g[row], c);
                for (int q = 0; q < c; ++q) {
                    const int s = base + q;
                    if (s < CAPG) cand_g[(size_t)row * CAPG + s] = candR[tid * CAPL + q];
                }
            }
        }
        if (!diag) {   // col-side writeout
            const int row = c0 + tid;
            const int c = (cntC[tid] < CAPL) ? cntC[tid] : CAPL;
            if (c > 0) {
                const int base = atomicAdd(&cnt_g[row], c);
                for (int q = 0; q < c; ++q) {
                    const int s = base + q;
                    if (s < CAPG) cand_g[(size_t)row * CAPG + s] = candC[tid * CAPL + q];
                }
            }
        }
    }
}

// ---------------- kernel 5: per-row top-21 stats + LID ----
__global__ __launch_bounds__(256) void finalize_kernel(const float* __restrict__ cand_g,
                                                       const int* __restrict__ cnt_g,
                                                       float* __restrict__ out) {
    const int tid  = threadIdx.x;
    const int lane = tid & 63;
    const int row  = blockIdx.x * 4 + (tid >> 6);

    int cnt = cnt_g[row];
    if (cnt > CAPG) cnt = CAPG;
    const float INFV = __uint_as_float(0x7F800000u);

    float v[7];
    unsigned b[7];
#pragma unroll
    for (int j = 0; j < 7; ++j) {
        const int s = lane + 64 * j;
        v[j] = (s < cnt) ? fmaxf(cand_g[(size_t)row * CAPG + s], 0.0f) : INFV;
        b[j] = __float_as_uint(v[j]);
    }

    unsigned lo = 0, hi = 0x7F7FFFFFu;
#pragma unroll
    for (int it = 0; it < 31; ++it) {
        const unsigned mid = (lo + hi) >> 1;
        int c = 0;
#pragma unroll
        for (int j = 0; j < 7; ++j) c += (b[j] <= mid);
        c = wred_sum_i(c);
        if (c >= TOPK) hi = mid; else lo = mid + 1;
    }
    const float th = __uint_as_float(lo);

    int clt = 0;
    float slt = 0.f, mn = INFV;
#pragma unroll
    for (int j = 0; j < 7; ++j) {
        if (b[j] < lo) {
            clt += 1;
            slt += sqrtf(fmaxf(v[j], 1e-12f));
        }
        mn = fminf(mn, v[j]);
    }
    clt = wred_sum_i(clt);
    slt = wred_sum_f(slt);
    mn  = wred_min_f(mn);

    if (lane == 0) {
        const float a20 = sqrtf(fmaxf(th, 1e-12f));
        const float a0  = sqrtf(fmaxf(mn, 1e-12f));
        const float S21 = slt + (float)(TOPK - clt) * a20;
        const float m   = (S21 - a0 - a20) * (1.0f / 19.0f);
        const float lid = m / (a20 - m);
        out[row] = -fabsf(logf(lid));
    }
}

extern "C" void kernel_launch(void* const* d_in, const int* in_sizes, int n_in,
                              void* d_out, int out_size, void* d_ws, size_t ws_size,
                              hipStream_t stream) {
    const float* X = (const float*)d_in[0];
    float* out = (float*)d_out;
    char* ws = (char*)d_ws;

    u16*   Xh    = (u16*)ws;                      // 12,582,912 B
    float* norms = (float*)(ws + 12582912);       //     32,768 B
    float* tauB  = (float*)(ws + 12615680);       //     32,768 B
    int*   cnt_g = (int*)(ws + 12648448);         //     32,768 B
    u16*   d2h   = (u16*)(ws + 12681216);         // 16,777,216 B (8192x1024 fp16)
    float* cand_g = (float*)(ws + 12681216);      // 14,680,064 B, aliases d2h

    prep_kernel<<<N_PTS / 4, 256, 0, stream>>>(X, Xh, norms, cnt_g);
    gemm_tau_kernel<<<512, 256, 0, stream>>>(Xh, norms, d2h);
    tau_select_kernel<<<N_PTS / 4, 256, 0, stream>>>(d2h, tauB);
    gemm_filter_sym<<<2080, 256, 0, stream>>>(Xh, norms, tauB, cand_g, cnt_g);
    finalize_kernel<<<N_PTS / 4, 256, 0, stream>>>(cand_g, cnt_g, out);
}

// Round 10
// 174.137 us; speedup vs baseline: 1.3065x; 1.0418x over previous
//
#include <hip/hip_runtime.h>
#include <hip/hip_fp16.h>

typedef unsigned short u16;
using f32x4 = __attribute__((ext_vector_type(4))) float;
using half8 = __attribute__((ext_vector_type(8))) _Float16;
using us8   = __attribute__((ext_vector_type(8))) unsigned short;
using us4   = __attribute__((ext_vector_type(4))) unsigned short;

#define N_PTS 8192
#define D_DIM 768
#define TOPK  21
#define KSTEPS 12
#define CAPL  5          // lambda=2.6/tile-side; E[excess>5]=0.074 -> ~39K spills total
#define CAPG  448        // global candidate slots per row (E~168, +21 sigma)

// ---------------- async global->LDS (16B per lane) ----------------
__device__ __forceinline__ void gload16(const void* g, void* l) {
    __builtin_amdgcn_global_load_lds(
        (const __attribute__((address_space(1))) void*)g,
        (__attribute__((address_space(3))) void*)l,
        16, 0, 0);
}

// ---------------- wave (64-lane) reductions ----------------
__device__ __forceinline__ int wred_sum_i(int c) {
#pragma unroll
    for (int o = 32; o >= 1; o >>= 1) c += __shfl_xor(c, o, 64);
    return c;
}
__device__ __forceinline__ float wred_sum_f(float c) {
#pragma unroll
    for (int o = 32; o >= 1; o >>= 1) c += __shfl_xor(c, o, 64);
    return c;
}
__device__ __forceinline__ float wred_min_f(float c) {
#pragma unroll
    for (int o = 32; o >= 1; o >>= 1) c = fminf(c, __shfl_xor(c, o, 64));
    return c;
}

// ---------------- kernel 1: fp32 -> fp16 + row norms (vectorized) ----
__global__ __launch_bounds__(256) void prep_kernel(const float* __restrict__ X,
                                                   u16* __restrict__ Xh,
                                                   float* __restrict__ norms,
                                                   int* __restrict__ cnt_g) {
    const int tid  = threadIdx.x;
    const int lane = tid & 63;
    const int row  = blockIdx.x * 4 + (tid >> 6);
    const float4* xr = (const float4*)(X + (size_t)row * D_DIM);
    us4* hr = (us4*)(Xh + (size_t)row * D_DIM);
    float s = 0.f;
#pragma unroll
    for (int j = 0; j < 3; ++j) {
        const float4 v = xr[lane + j * 64];
        _Float16 h0 = (_Float16)v.x, h1 = (_Float16)v.y,
                 h2 = (_Float16)v.z, h3 = (_Float16)v.w;
        us4 u;
        u[0] = __builtin_bit_cast(u16, h0);
        u[1] = __builtin_bit_cast(u16, h1);
        u[2] = __builtin_bit_cast(u16, h2);
        u[3] = __builtin_bit_cast(u16, h3);
        hr[lane + j * 64] = u;
        const float f0 = (float)h0, f1 = (float)h1, f2 = (float)h2, f3 = (float)h3;
        s += f0 * f0 + f1 * f1 + f2 * f2 + f3 * f3;
    }
#pragma unroll
    for (int o = 32; o >= 1; o >>= 1) s += __shfl_down(s, o, 64);
    if (lane == 0) {
        norms[row] = s;
        cnt_g[row] = 0;
    }
}

// ---------------- kernel 2: sample GEMM (cols 0..1023) -> d2 as fp16 ----
__global__ __launch_bounds__(256, 4) void gemm_tau_kernel(const u16* __restrict__ Xh,
                                                          const float* __restrict__ norms,
                                                          u16* __restrict__ d2h) {
    __shared__ __align__(16) u16 As[128 * 64];
    __shared__ __align__(16) u16 Bs[128 * 64];
    __shared__ float nAs[128];
    __shared__ float nBs[128];

    const int tid  = threadIdx.x;
    const int lane = tid & 63;
    const int wid  = tid >> 6;
    const int wr   = wid >> 1;
    const int wc   = wid & 1;
    const int l16  = lane >> 4;
    const int l15  = lane & 15;

    const int bid = blockIdx.x;
    const int swz = (bid & 7) * 64 + (bid >> 3);
    const int rowTile = swz >> 3;
    const int chunk   = swz & 7;
    const int r0 = rowTile * 128;
    const int cb = chunk * 128;

    if (tid < 128) {
        nAs[tid] = norms[r0 + tid];
        nBs[tid] = norms[cb + tid];
    }

    const int rb   = tid >> 3;
    const int cole = (tid & 7) * 8;
    const int lofs = tid * 8;

    f32x4 acc[4][4];
#pragma unroll
    for (int m = 0; m < 4; ++m)
#pragma unroll
        for (int n = 0; n < 4; ++n) {
            f32x4 z = {0.f, 0.f, 0.f, 0.f};
            acc[m][n] = z;
        }

    for (int ks = 0; ks < KSTEPS; ++ks) {
        const int kofs = ks * 64;
#pragma unroll
        for (int i = 0; i < 4; ++i) {
            const int r = i * 32 + rb;
            gload16(Xh + (size_t)(r0 + r) * D_DIM + kofs + cole, &As[i * 2048 + lofs]);
            gload16(Xh + (size_t)(cb + r) * D_DIM + kofs + cole, &Bs[i * 2048 + lofs]);
        }
        __syncthreads();
#pragma unroll
        for (int kk = 0; kk < 2; ++kk) {
            const int ko = kk * 32 + l16 * 8;
            half8 af[4], bf[4];
#pragma unroll
            for (int m = 0; m < 4; ++m)
                af[m] = *reinterpret_cast<const half8*>(&As[(wr * 64 + m * 16 + l15) * 64 + ko]);
#pragma unroll
            for (int n = 0; n < 4; ++n)
                bf[n] = *reinterpret_cast<const half8*>(&Bs[(wc * 64 + n * 16 + l15) * 64 + ko]);
#pragma unroll
            for (int m = 0; m < 4; ++m)
#pragma unroll
                for (int n = 0; n < 4; ++n)
                    acc[m][n] = __builtin_amdgcn_mfma_f32_16x16x32_f16(af[m], bf[n], acc[m][n], 0, 0, 0);
        }
        __syncthreads();
    }

    float nAr[4][4], nBc[4];
#pragma unroll
    for (int m = 0; m < 4; ++m)
#pragma unroll
        for (int r = 0; r < 4; ++r) nAr[m][r] = nAs[wr * 64 + m * 16 + l16 * 4 + r];
#pragma unroll
    for (int n = 0; n < 4; ++n) nBc[n] = nBs[wc * 64 + n * 16 + l15];

#pragma unroll
    for (int m = 0; m < 4; ++m)
#pragma unroll
        for (int n = 0; n < 4; ++n)
#pragma unroll
            for (int r = 0; r < 4; ++r) {
                const int ri = r0 + wr * 64 + m * 16 + l16 * 4 + r;
                const int ci = cb + wc * 64 + n * 16 + l15;
                float d2 = fmaxf(nAr[m][r] + nBc[n] - 2.0f * acc[m][n][r], 0.0f);
                _Float16 h = (_Float16)d2;
                d2h[(size_t)ri * 1024 + ci] = __builtin_bit_cast(u16, h);
            }
}

// ---------------- kernel 3: per-row 21st-smallest of sample (bit search) ----
__global__ __launch_bounds__(256) void tau_select_kernel(const u16* __restrict__ d2h,
                                                         float* __restrict__ tauB) {
    const int tid  = threadIdx.x;
    const int lane = tid & 63;
    const int row  = blockIdx.x * 4 + (tid >> 6);

    const us8* p = (const us8*)(d2h + (size_t)row * 1024);
    us8 v0 = p[lane * 2];
    us8 v1 = p[lane * 2 + 1];

    unsigned lo = 0, hi = 0x7BFF;
#pragma unroll
    for (int it = 0; it < 15; ++it) {
        const unsigned mid = (lo + hi) >> 1;
        int c = 0;
#pragma unroll
        for (int j = 0; j < 8; ++j) c += ((unsigned)v0[j] <= mid) + ((unsigned)v1[j] <= mid);
        c = wred_sum_i(c);
        if (c >= TOPK) hi = mid; else lo = mid + 1;
    }
    if (lane == 0) {
        u16 b = (u16)lo;
        _Float16 h = __builtin_bit_cast(_Float16, b);
        tauB[row] = (float)h + 2.0f;   // upper bound on true 21st d2 + fp16 slack
    }
}

// ---------------- kernel 4: SYMMETRIC upper-triangle GEMM + two-sided filter ----
// 2080 = 64*65/2 tiles of 128x128 (i<=j); off-diag tiles emit row- AND col-side.
// LDS = exactly 40960 B -> 4 blocks/CU (R3-verified at this size).
__global__ __launch_bounds__(256, 4) void gemm_filter_sym(const u16* __restrict__ Xh,
                                                          const float* __restrict__ norms,
                                                          const float* __restrict__ tauB,
                                                          float* __restrict__ cand_g,
                                                          int* __restrict__ cnt_g) {
    __shared__ __align__(16) u16 As[128 * 64];       // 16384 B
    __shared__ __align__(16) u16 Bs[128 * 64];       // 16384 B
    __shared__ float candR[128 * CAPL];              //  2560 B
    __shared__ float candC[128 * CAPL];              //  2560 B
    __shared__ int   cntR[128];                      //   512 B
    __shared__ int   cntC[128];                      //   512 B
    __shared__ float nAs[128], nBs[128], tA[128], tB[128];   // 2048 B  => 40960 total

    const int tid  = threadIdx.x;
    const int lane = tid & 63;
    const int wid  = tid >> 6;
    const int wr   = wid >> 1;
    const int wc   = wid & 1;
    const int l16  = lane >> 4;
    const int l15  = lane & 15;

    // XCD swizzle (2080 = 8 * 260) then triangular decode: b = j*(j+1)/2 + i, i<=j
    const int b = (blockIdx.x & 7) * 260 + (blockIdx.x >> 3);
    int j = (int)((sqrtf(8.0f * (float)b + 1.0f) - 1.0f) * 0.5f);
    while ((j + 1) * (j + 2) / 2 <= b) ++j;
    while (j * (j + 1) / 2 > b) --j;
    const int i = b - j * (j + 1) / 2;
    const int r0 = i * 128;
    const int c0 = j * 128;
    const bool diag = (i == j);

    if (tid < 128) {
        nAs[tid] = norms[r0 + tid];
        tA[tid]  = tauB[r0 + tid];
        nBs[tid] = norms[c0 + tid];
        tB[tid]  = tauB[c0 + tid];
        cntR[tid] = 0;
        cntC[tid] = 0;
    }

    // staging geometry: 8 lanes per 128B row; T2 source-side XOR swizzle
    const int rb  = tid >> 3;
    const int chS = (tid & 7) ^ ((tid >> 3) & 7);
    const int lofs = tid * 8;

    f32x4 acc[4][4];
#pragma unroll
    for (int m = 0; m < 4; ++m)
#pragma unroll
        for (int n = 0; n < 4; ++n) {
            f32x4 z = {0.f, 0.f, 0.f, 0.f};
            acc[m][n] = z;
        }

    for (int ks = 0; ks < KSTEPS; ++ks) {
        const int kofs = ks * 64 + chS * 8;
#pragma unroll
        for (int it = 0; it < 4; ++it) {
            const int r = it * 32 + rb;
            gload16(Xh + (size_t)(r0 + r) * D_DIM + kofs, &As[it * 2048 + lofs]);
            gload16(Xh + (size_t)(c0 + r) * D_DIM + kofs, &Bs[it * 2048 + lofs]);
        }
        __syncthreads();
#pragma unroll
        for (int kk = 0; kk < 2; ++kk) {
            half8 af[4], bf[4];
#pragma unroll
            for (int m = 0; m < 4; ++m) {
                const int ra = wr * 64 + m * 16 + l15;
                const int ch = (kk * 4 + l16) ^ (ra & 7);
                af[m] = *reinterpret_cast<const half8*>(&As[ra * 64 + ch * 8]);
            }
#pragma unroll
            for (int n = 0; n < 4; ++n) {
                const int rc = wc * 64 + n * 16 + l15;
                const int ch = (kk * 4 + l16) ^ (rc & 7);
                bf[n] = *reinterpret_cast<const half8*>(&Bs[rc * 64 + ch * 8]);
            }
#pragma unroll
            for (int m = 0; m < 4; ++m)
#pragma unroll
                for (int n = 0; n < 4; ++n)
                    acc[m][n] = __builtin_amdgcn_mfma_f32_16x16x32_f16(af[m], bf[n], acc[m][n], 0, 0, 0);
        }
        __syncthreads();
    }

    // ---- two-sided filter epilogue ----
    float nBc[4], tBc[4];
#pragma unroll
    for (int n = 0; n < 4; ++n) {
        const int ci = wc * 64 + n * 16 + l15;
        nBc[n] = nBs[ci];
        tBc[n] = tB[ci];
    }

#pragma unroll
    for (int m = 0; m < 4; ++m)
#pragma unroll
        for (int r = 0; r < 4; ++r) {
            const int ri = wr * 64 + m * 16 + l16 * 4 + r;
            const float na = nAs[ri];
            const float ta = tA[ri];
#pragma unroll
            for (int n = 0; n < 4; ++n) {
                const float val = na + nBc[n] - 2.0f * acc[m][n][r];
                if (val < ta) {                      // row-side candidate
                    const int idx = atomicAdd(&cntR[ri], 1);
                    if (idx < CAPL) candR[ri * CAPL + idx] = val;
                    else {
                        const int g = atomicAdd(&cnt_g[r0 + ri], 1);
                        if (g < CAPG) cand_g[(size_t)(r0 + ri) * CAPG + g] = val;
                    }
                }
                if (!diag && val < tBc[n]) {         // col-side candidate (symmetry)
                    const int ci = wc * 64 + n * 16 + l15;
                    const int idx = atomicAdd(&cntC[ci], 1);
                    if (idx < CAPL) candC[ci * CAPL + idx] = val;
                    else {
                        const int g = atomicAdd(&cnt_g[c0 + ci], 1);
                        if (g < CAPG) cand_g[(size_t)(c0 + ci) * CAPG + g] = val;
                    }
                }
            }
        }

    __syncthreads();
    if (tid < 128) {
        {   // row-side writeout
            const int row = r0 + tid;
            const int c = (cntR[tid] < CAPL) ? cntR[tid] : CAPL;
            if (c > 0) {
                const int base = atomicAdd(&cnt_g[row], c);
                for (int q = 0; q < c; ++q) {
                    const int s = base + q;
                    if (s < CAPG) cand_g[(size_t)row * CAPG + s] = candR[tid * CAPL + q];
                }
            }
        }
        if (!diag) {   // col-side writeout
            const int row = c0 + tid;
            const int c = (cntC[tid] < CAPL) ? cntC[tid] : CAPL;
            if (c > 0) {
                const int base = atomicAdd(&cnt_g[row], c);
                for (int q = 0; q < c; ++q) {
                    const int s = base + q;
                    if (s < CAPG) cand_g[(size_t)row * CAPG + s] = candC[tid * CAPL + q];
                }
            }
        }
    }
}

// ---------------- kernel 5: per-row top-21 stats + LID ----
__global__ __launch_bounds__(256) void finalize_kernel(const float* __restrict__ cand_g,
                                                       const int* __restrict__ cnt_g,
                                                       float* __restrict__ out) {
    const int tid  = threadIdx.x;
    const int lane = tid & 63;
    const int row  = blockIdx.x * 4 + (tid >> 6);

    int cnt = cnt_g[row];
    if (cnt > CAPG) cnt = CAPG;
    const float INFV = __uint_as_float(0x7F800000u);

    float v[7];
    unsigned b[7];
#pragma unroll
    for (int j = 0; j < 7; ++j) {
        const int s = lane + 64 * j;
        v[j] = (s < cnt) ? fmaxf(cand_g[(size_t)row * CAPG + s], 0.0f) : INFV;
        b[j] = __float_as_uint(v[j]);
    }

    unsigned lo = 0, hi = 0x7F7FFFFFu;
#pragma unroll
    for (int it = 0; it < 31; ++it) {
        const unsigned mid = (lo + hi) >> 1;
        int c = 0;
#pragma unroll
        for (int j = 0; j < 7; ++j) c += (b[j] <= mid);
        c = wred_sum_i(c);
        if (c >= TOPK) hi = mid; else lo = mid + 1;
    }
    const float th = __uint_as_float(lo);

    int clt = 0;
    float slt = 0.f, mn = INFV;
#pragma unroll
    for (int j = 0; j < 7; ++j) {
        if (b[j] < lo) {
            clt += 1;
            slt += sqrtf(fmaxf(v[j], 1e-12f));
        }
        mn = fminf(mn, v[j]);
    }
    clt = wred_sum_i(clt);
    slt = wred_sum_f(slt);
    mn  = wred_min_f(mn);

    if (lane == 0) {
        const float a20 = sqrtf(fmaxf(th, 1e-12f));
        const float a0  = sqrtf(fmaxf(mn, 1e-12f));
        const float S21 = slt + (float)(TOPK - clt) * a20;
        const float m   = (S21 - a0 - a20) * (1.0f / 19.0f);
        const float lid = m / (a20 - m);
        out[row] = -fabsf(logf(lid));
    }
}

extern "C" void kernel_launch(void* const* d_in, const int* in_sizes, int n_in,
                              void* d_out, int out_size, void* d_ws, size_t ws_size,
                              hipStream_t stream) {
    const float* X = (const float*)d_in[0];
    float* out = (float*)d_out;
    char* ws = (char*)d_ws;

    u16*   Xh    = (u16*)ws;                      // 12,582,912 B
    float* norms = (float*)(ws + 12582912);       //     32,768 B
    float* tauB  = (float*)(ws + 12615680);       //     32,768 B
    int*   cnt_g = (int*)(ws + 12648448);         //     32,768 B
    u16*   d2h   = (u16*)(ws + 12681216);         // 16,777,216 B (8192x1024 fp16)
    float* cand_g = (float*)(ws + 12681216);      // 14,680,064 B, aliases d2h

    prep_kernel<<<N_PTS / 4, 256, 0, stream>>>(X, Xh, norms, cnt_g);
    gemm_tau_kernel<<<512, 256, 0, stream>>>(Xh, norms, d2h);
    tau_select_kernel<<<N_PTS / 4, 256, 0, stream>>>(d2h, tauB);
    gemm_filter_sym<<<2080, 256, 0, stream>>>(Xh, norms, tauB, cand_g, cnt_g);
    finalize_kernel<<<N_PTS / 4, 256, 0, stream>>>(cand_g, cnt_g, out);
}